// Round 4
// baseline (815.119 us; speedup 1.0000x reference)
//
#include <hip/hip_runtime.h>
#include <hip/hip_bf16.h>

#define N_NODES 50000
#define N_EDGES 800000
#define DIM 128
#define N_LAYERS 5
#define BN_EPS 1e-3f

typedef __attribute__((ext_vector_type(8))) short bf16x8;
typedef __attribute__((ext_vector_type(4))) float f32x4;

__device__ __forceinline__ unsigned short f2bf(float f) {
    unsigned int v = __builtin_bit_cast(unsigned int, f);
    v += 0x7fffu + ((v >> 16) & 1u);
    return (unsigned short)(v >> 16);
}
__device__ __forceinline__ float bflo(unsigned int v) {
    return __builtin_bit_cast(float, v << 16);
}
__device__ __forceinline__ float bfhi(unsigned int v) {
    return __builtin_bit_cast(float, v & 0xffff0000u);
}

// ---- setup kernels -------------------------------------------------------

// copy x -> out chunk 0 (fp32) + hb0 (bf16 shadow); also zero cnt[]
__global__ void init_zero_kernel(const float* __restrict__ x, float* __restrict__ out,
                                 unsigned short* __restrict__ hb, int* __restrict__ cnt) {
    int t = blockIdx.x * blockDim.x + threadIdx.x;
    if (t < (N_NODES * DIM) / 4) {
        float4 v = ((const float4*)x)[t];
        ((float4*)out)[t] = v;
        unsigned short u[4] = {f2bf(v.x), f2bf(v.y), f2bf(v.z), f2bf(v.w)};
        *(uint2*)(hb + t * 4) = *(uint2*)u;
    }
    int z = t - (N_NODES * DIM) / 4;
    if (z >= 0 && z < N_NODES) cnt[z] = 0;
}

__global__ void hist_kernel(const int* __restrict__ dst, int* __restrict__ cnt) {
    int e = blockIdx.x * blockDim.x + threadIdx.x;
    if (e < N_EDGES) atomicAdd(&cnt[dst[e]], 1);
}

// single-block exclusive scan of cnt[0..N_NODES) -> row_start, cursor
__global__ __launch_bounds__(1024) void scan_kernel(const int* __restrict__ cnt,
                                                    int* __restrict__ row_start,
                                                    int* __restrict__ cursor) {
    __shared__ int wsum[16];
    __shared__ int s_carry;
    const int tid = threadIdx.x;
    const int lane = tid & 63, wave = tid >> 6;
    if (tid == 0) s_carry = 0;
    __syncthreads();
    for (int base = 0; base < N_NODES; base += 4096) {
        int i0 = base + tid * 4;
        int v[4];
#pragma unroll
        for (int j = 0; j < 4; j++) {
            int i = i0 + j;
            v[j] = (i < N_NODES) ? cnt[i] : 0;
        }
        int s = v[0] + v[1] + v[2] + v[3];
        int x = s;
#pragma unroll
        for (int off = 1; off < 64; off <<= 1) {
            int t = __shfl_up(x, off, 64);
            if (lane >= off) x += t;
        }
        if (lane == 63) wsum[wave] = x;
        __syncthreads();
        if (wave == 0) {
            int w = (lane < 16) ? wsum[lane] : 0;
#pragma unroll
            for (int off = 1; off < 16; off <<= 1) {
                int t = __shfl_up(w, off, 64);
                if (lane >= off) w += t;
            }
            if (lane < 16) wsum[lane] = w;
        }
        __syncthreads();
        int waveoff = (wave > 0) ? wsum[wave - 1] : 0;
        int carry = s_carry;
        int run = carry + waveoff + (x - s);
#pragma unroll
        for (int j = 0; j < 4; j++) {
            int i = i0 + j;
            if (i < N_NODES) { row_start[i] = run; cursor[i] = run; }
            run += v[j];
        }
        __syncthreads();
        if (tid == 1023) s_carry = carry + wsum[15];
        __syncthreads();
    }
    if (tid == 0) row_start[N_NODES] = s_carry;
}

__global__ void fill_kernel(const int* __restrict__ src, const int* __restrict__ dst,
                            int* __restrict__ cursor, int* __restrict__ col) {
    int e = blockIdx.x * blockDim.x + threadIdx.x;
    if (e < N_EDGES) {
        int d = dst[e];
        int pos = atomicAdd(&cursor[d], 1);
        col[pos] = src[e];
    }
}

// pack W1/W2 (fp32->bf16) into B-fragment order + fold BN scale/shift
__global__ void prep_kernel(const float* __restrict__ W1, const float* __restrict__ W2,
                            unsigned short* __restrict__ wp,
                            const float* __restrict__ gamma, const float* __restrict__ beta,
                            const float* __restrict__ mean, const float* __restrict__ var,
                            float* __restrict__ scale, float* __restrict__ shift) {
    int t = blockIdx.x * blockDim.x + threadIdx.x;
    if (t < N_LAYERS * 2 * 2048) {
        int mat = t >> 11;
        int r = t & 2047;
        int ks = r >> 9, nt = (r >> 6) & 7, lane = r & 63;
        int layer = mat >> 1;
        const float* W = ((mat & 1) ? W2 : W1) + layer * DIM * DIM;
        int n = nt * 16 + (lane & 15);
        int kb = ks * 32 + (lane >> 4) * 8;
        unsigned short u[8];
#pragma unroll
        for (int j = 0; j < 8; j++) u[j] = f2bf(W[(kb + j) * DIM + n]);
        *(uint4*)(wp + (size_t)mat * 16384 + ((ks * 8 + nt) * 64 + lane) * 8) = *(uint4*)u;
    }
    int i = t - N_LAYERS * 2 * 2048;
    if (i >= 0 && i < N_LAYERS * DIM) {
        float sc = gamma[i] * rsqrtf(var[i] + BN_EPS);
        scale[i] = sc;
        shift[i] = beta[i] - mean[i] * sc;
    }
}

// ---- fused layer: pool -> Linear1 -> ReLU -> Linear2 -> BN -> ReLU -------
__global__ __launch_bounds__(256) void layer_kernel(
    const unsigned short* __restrict__ hb_in,
    const int* __restrict__ row_start,
    const int* __restrict__ col,
    const float* __restrict__ eps_l,
    const unsigned short* __restrict__ wp1,
    const unsigned short* __restrict__ wp2,
    const float* __restrict__ b1,
    const float* __restrict__ b2,
    const float* __restrict__ bnscale,
    const float* __restrict__ bnshift,
    float* __restrict__ h_out,
    unsigned short* __restrict__ hb_out) {
    // A-fragment staging; each wave owns afrag[wave] (wave-private, no barriers)
    __shared__ __align__(16) unsigned short afrag[4][4][64][8];  // 16 KB
    const int tid = threadIdx.x;
    const int wave = tid >> 6, lane = tid & 63;
    const int m0 = blockIdx.x * 64 + wave * 16;   // this wave's 16 rows
    const float ev = 1.0f + eps_l[0];
    const int c = lane * 2;                       // this lane's 2 columns
    const int ks_w = c >> 5, idx_w = (((c >> 3) & 3) << 4), j_w = c & 7;

    // ---- pooling: 16 nodes, lane covers cols c, c+1 (one dword per row) ----
    for (int r = 0; r < 16; r++) {
        const int n = m0 + r;
        float a0 = 0.f, a1 = 0.f;
        if (n < N_NODES) {
            unsigned int sv = *(const unsigned int*)(hb_in + n * DIM + c);
            a0 = ev * bflo(sv);
            a1 = ev * bfhi(sv);
            const int s0 = row_start[n], s1 = row_start[n + 1];
            for (int base = s0; base < s1; base += 64) {
                const int nn = (s1 - base < 64) ? (s1 - base) : 64;
                int ci = (base + lane < s1) ? col[base + lane] : 0;
                int j = 0;
                for (; j + 7 < nn; j += 8) {
                    int s[8];
                    unsigned int v[8];
#pragma unroll
                    for (int q = 0; q < 8; q++) s[q] = __shfl(ci, j + q, 64);
#pragma unroll
                    for (int q = 0; q < 8; q++)
                        v[q] = *(const unsigned int*)(hb_in + s[q] * DIM + c);
#pragma unroll
                    for (int q = 0; q < 8; q++) { a0 += bflo(v[q]); a1 += bfhi(v[q]); }
                }
                for (; j < nn; j++) {
                    int sq = __shfl(ci, j, 64);
                    unsigned int vq = *(const unsigned int*)(hb_in + sq * DIM + c);
                    a0 += bflo(vq); a1 += bfhi(vq);
                }
            }
        }
        unsigned short u[2] = {f2bf(a0), f2bf(a1)};
        *(unsigned int*)&afrag[wave][ks_w][idx_w | r][j_w] = *(unsigned int*)u;
    }

    // ---- GEMM1 ----
    bf16x8 a[4];
#pragma unroll
    for (int ks = 0; ks < 4; ks++) a[ks] = *(const bf16x8*)(&afrag[wave][ks][lane][0]);

    f32x4 acc[8];
#pragma unroll
    for (int nt = 0; nt < 8; nt++) {
        acc[nt] = (f32x4){0.f, 0.f, 0.f, 0.f};
#pragma unroll
        for (int ks = 0; ks < 4; ks++) {
            bf16x8 b = *(const bf16x8*)(wp1 + ((ks * 8 + nt) * 64 + lane) * 8);
            acc[nt] = __builtin_amdgcn_mfma_f32_16x16x32_bf16(a[ks], b, acc[nt], 0, 0, 0);
        }
    }

    // bias + ReLU, z1 -> same LDS region in A-frag layout (a[] is in regs; WAR safe:
    // same-wave DS ops execute in order)
    const int colc = lane & 15;
    const int quad = lane >> 4;
#pragma unroll
    for (int nt = 0; nt < 8; nt++) {
        int n = nt * 16 + colc;
        float bias = b1[n];
#pragma unroll
        for (int r = 0; r < 4; r++) {
            float v = acc[nt][r] + bias;
            v = v > 0.f ? v : 0.f;
            int row16 = quad * 4 + r;
            afrag[wave][n >> 5][(((n >> 3) & 3) << 4) | row16][n & 7] = f2bf(v);
        }
    }

#pragma unroll
    for (int ks = 0; ks < 4; ks++) a[ks] = *(const bf16x8*)(&afrag[wave][ks][lane][0]);

    // ---- GEMM2 ----
    f32x4 acc2[8];
#pragma unroll
    for (int nt = 0; nt < 8; nt++) {
        acc2[nt] = (f32x4){0.f, 0.f, 0.f, 0.f};
#pragma unroll
        for (int ks = 0; ks < 4; ks++) {
            bf16x8 b = *(const bf16x8*)(wp2 + ((ks * 8 + nt) * 64 + lane) * 8);
            acc2[nt] = __builtin_amdgcn_mfma_f32_16x16x32_bf16(a[ks], b, acc2[nt], 0, 0, 0);
        }
    }

    // ---- epilogue: +b2, BN, ReLU; fp32 out chunk + bf16 shadow ----
#pragma unroll
    for (int nt = 0; nt < 8; nt++) {
        int n = nt * 16 + colc;
        float bias = b2[n];
        float sc = bnscale[n], sh = bnshift[n];
#pragma unroll
        for (int r = 0; r < 4; r++) {
            int row = m0 + quad * 4 + r;
            if (row < N_NODES) {
                float z = acc2[nt][r] + bias;
                z = z * sc + sh;
                z = z > 0.f ? z : 0.f;
                h_out[row * DIM + n] = z;
                hb_out[row * DIM + n] = f2bf(z);
            }
        }
    }
}

// ---- launch --------------------------------------------------------------

extern "C" void kernel_launch(void* const* d_in, const int* in_sizes, int n_in,
                              void* d_out, int out_size, void* d_ws, size_t ws_size,
                              hipStream_t stream) {
    const float* x     = (const float*)d_in[0];
    const int* esrc    = (const int*)d_in[1];
    const int* edst    = (const int*)d_in[2];
    const float* eps   = (const float*)d_in[3];
    const float* W1    = (const float*)d_in[4];
    const float* b1    = (const float*)d_in[5];
    const float* W2    = (const float*)d_in[6];
    const float* b2    = (const float*)d_in[7];
    const float* gam   = (const float*)d_in[8];
    const float* bet   = (const float*)d_in[9];
    const float* bmean = (const float*)d_in[10];
    const float* bvar  = (const float*)d_in[11];
    float* out = (float*)d_out;

    char* ws = (char*)d_ws;
    unsigned short* hb0   = (unsigned short*)(ws);               // 12,800,000 B
    unsigned short* hb1   = (unsigned short*)(ws + 12800000);    // 12,800,000 B
    int*   col        = (int*)  (ws + 25600000);                 //  3,200,000 B
    int*   row_start  = (int*)  (ws + 28800000);                 //    200,004 B
    int*   cursor     = (int*)  (ws + 29000008);                 //    200,000 B
    int*   cnt        = (int*)  (ws + 29200008);                 //    200,000 B
    unsigned short* wpack = (unsigned short*)(ws + 29400008);    //    327,680 B
    float* bnscale    = (float*)(ws + 29727688);                 //      2,560 B
    float* bnshift    = (float*)(ws + 29730248);                 //      2,560 B

    init_zero_kernel<<<((N_NODES * DIM) / 4 + N_NODES + 255) / 256, 256, 0, stream>>>(
        x, out, hb0, cnt);
    hist_kernel<<<(N_EDGES + 255) / 256, 256, 0, stream>>>(edst, cnt);
    scan_kernel<<<1, 1024, 0, stream>>>(cnt, row_start, cursor);
    fill_kernel<<<(N_EDGES + 255) / 256, 256, 0, stream>>>(esrc, edst, cursor, col);
    prep_kernel<<<(N_LAYERS * 2 * 2048 + N_LAYERS * DIM + 255) / 256, 256, 0, stream>>>(
        W1, W2, wpack, gam, bet, bmean, bvar, bnscale, bnshift);

    const int blocks = (N_NODES + 63) / 64;  // 782
    unsigned short* hbuf[2] = {hb0, hb1};
    for (int l = 0; l < N_LAYERS; l++) {
        float* h_next = out + (size_t)(l + 1) * N_NODES * DIM;
        layer_kernel<<<blocks, 256, 0, stream>>>(
            hbuf[l & 1], row_start, col, eps + l,
            wpack + (size_t)(l * 2) * 16384,
            wpack + (size_t)(l * 2 + 1) * 16384,
            b1 + l * DIM, b2 + l * DIM,
            bnscale + l * DIM, bnshift + l * DIM,
            h_next, hbuf[(l + 1) & 1]);
    }
}

// Round 6
// 573.071 us; speedup vs baseline: 1.4224x; 1.4224x over previous
//
#include <hip/hip_runtime.h>
#include <hip/hip_bf16.h>

#define N_NODES 50000
#define N_EDGES 800000
#define DIM 128
#define N_LAYERS 5
#define BN_EPS 1e-3f

typedef __attribute__((ext_vector_type(8))) short bf16x8;
typedef __attribute__((ext_vector_type(4))) float f32x4;

__device__ __forceinline__ unsigned short f2bf(float f) {
    unsigned int v = __builtin_bit_cast(unsigned int, f);
    v += 0x7fffu + ((v >> 16) & 1u);
    return (unsigned short)(v >> 16);
}
__device__ __forceinline__ float bflo(unsigned int v) {
    return __builtin_bit_cast(float, v << 16);
}
__device__ __forceinline__ float bfhi(unsigned int v) {
    return __builtin_bit_cast(float, v & 0xffff0000u);
}

// ---- setup kernels -------------------------------------------------------

// copy x -> out chunk 0 (fp32) + hb0 (bf16 shadow); also zero cnt[]
__global__ void init_zero_kernel(const float* __restrict__ x, float* __restrict__ out,
                                 unsigned short* __restrict__ hb, int* __restrict__ cnt) {
    int t = blockIdx.x * blockDim.x + threadIdx.x;
    if (t < (N_NODES * DIM) / 4) {
        f32x4 v = ((const f32x4*)x)[t];
        __builtin_nontemporal_store(v, (f32x4*)out + t);
        unsigned short u[4] = {f2bf(v.x), f2bf(v.y), f2bf(v.z), f2bf(v.w)};
        *(uint2*)(hb + t * 4) = *(uint2*)u;
    }
    int z = t - (N_NODES * DIM) / 4;
    if (z >= 0 && z < N_NODES) cnt[z] = 0;
}

__global__ void hist_kernel(const int* __restrict__ dst, int* __restrict__ cnt) {
    int e = blockIdx.x * blockDim.x + threadIdx.x;
    if (e < N_EDGES) atomicAdd(&cnt[dst[e]], 1);
}

// single-block exclusive scan of cnt[0..N_NODES) -> row_start, cursor
__global__ __launch_bounds__(1024) void scan_kernel(const int* __restrict__ cnt,
                                                    int* __restrict__ row_start,
                                                    int* __restrict__ cursor) {
    __shared__ int wsum[16];
    __shared__ int s_carry;
    const int tid = threadIdx.x;
    const int lane = tid & 63, wave = tid >> 6;
    if (tid == 0) s_carry = 0;
    __syncthreads();
    for (int base = 0; base < N_NODES; base += 4096) {
        int i0 = base + tid * 4;
        int v[4];
#pragma unroll
        for (int j = 0; j < 4; j++) {
            int i = i0 + j;
            v[j] = (i < N_NODES) ? cnt[i] : 0;
        }
        int s = v[0] + v[1] + v[2] + v[3];
        int x = s;
#pragma unroll
        for (int off = 1; off < 64; off <<= 1) {
            int t = __shfl_up(x, off, 64);
            if (lane >= off) x += t;
        }
        if (lane == 63) wsum[wave] = x;
        __syncthreads();
        if (wave == 0) {
            int w = (lane < 16) ? wsum[lane] : 0;
#pragma unroll
            for (int off = 1; off < 16; off <<= 1) {
                int t = __shfl_up(w, off, 64);
                if (lane >= off) w += t;
            }
            if (lane < 16) wsum[lane] = w;
        }
        __syncthreads();
        int waveoff = (wave > 0) ? wsum[wave - 1] : 0;
        int carry = s_carry;
        int run = carry + waveoff + (x - s);
#pragma unroll
        for (int j = 0; j < 4; j++) {
            int i = i0 + j;
            if (i < N_NODES) { row_start[i] = run; cursor[i] = run; }
            run += v[j];
        }
        __syncthreads();
        if (tid == 1023) s_carry = carry + wsum[15];
        __syncthreads();
    }
    if (tid == 0) row_start[N_NODES] = s_carry;
}

__global__ void fill_kernel(const int* __restrict__ src, const int* __restrict__ dst,
                            int* __restrict__ cursor, int* __restrict__ col) {
    int e = blockIdx.x * blockDim.x + threadIdx.x;
    if (e < N_EDGES) {
        int d = dst[e];
        int pos = atomicAdd(&cursor[d], 1);
        col[pos] = src[e];
    }
}

// pack W1/W2 (fp32->bf16) into B-fragment order + fold BN scale/shift
__global__ void prep_kernel(const float* __restrict__ W1, const float* __restrict__ W2,
                            unsigned short* __restrict__ wp,
                            const float* __restrict__ gamma, const float* __restrict__ beta,
                            const float* __restrict__ mean, const float* __restrict__ var,
                            float* __restrict__ scale, float* __restrict__ shift) {
    int t = blockIdx.x * blockDim.x + threadIdx.x;
    if (t < N_LAYERS * 2 * 2048) {
        int mat = t >> 11;
        int r = t & 2047;
        int ks = r >> 9, nt = (r >> 6) & 7, lane = r & 63;
        int layer = mat >> 1;
        const float* W = ((mat & 1) ? W2 : W1) + layer * DIM * DIM;
        int n = nt * 16 + (lane & 15);
        int kb = ks * 32 + (lane >> 4) * 8;
        unsigned short u[8];
#pragma unroll
        for (int j = 0; j < 8; j++) u[j] = f2bf(W[(kb + j) * DIM + n]);
        *(uint4*)(wp + (size_t)mat * 16384 + ((ks * 8 + nt) * 64 + lane) * 8) = *(uint4*)u;
    }
    int i = t - N_LAYERS * 2 * 2048;
    if (i >= 0 && i < N_LAYERS * DIM) {
        float sc = gamma[i] * rsqrtf(var[i] + BN_EPS);
        scale[i] = sc;
        shift[i] = beta[i] - mean[i] * sc;
    }
}

// ---- per-layer kernels ---------------------------------------------------

// one wave per node; lane i holds cols 2i, 2i+1 (one dword of 2 bf16 per row).
// 8 independent row-gathers in flight; masked accumulate kills the serial tail.
__global__ __launch_bounds__(256) void pool_kernel(const unsigned short* __restrict__ hb,
                                                   const int* __restrict__ row_start,
                                                   const int* __restrict__ col,
                                                   const float* __restrict__ eps_l,
                                                   unsigned short* __restrict__ pooled_b) {
    const int wave = threadIdx.x >> 6, lane = threadIdx.x & 63;
    const int n = blockIdx.x * 4 + wave;
    if (n >= N_NODES) return;
    const float ev = 1.0f + eps_l[0];
    const int s0 = row_start[n], s1 = row_start[n + 1];
    const int c2 = lane * 2;

    unsigned int sv = *(const unsigned int*)(hb + n * DIM + c2);
    float a0 = ev * bflo(sv);
    float a1 = ev * bfhi(sv);

    for (int base = s0; base < s1; base += 64) {
        const int nn = (s1 - base < 64) ? (s1 - base) : 64;
        int ci = (base + lane < s1) ? col[base + lane] : 0;
        for (int j = 0; j < nn; j += 8) {
            int s[8];
            unsigned int v[8];
#pragma unroll
            for (int q = 0; q < 8; q++) s[q] = __shfl(ci, j + q, 64);
#pragma unroll
            for (int q = 0; q < 8; q++)
                v[q] = *(const unsigned int*)(hb + s[q] * DIM + c2);
#pragma unroll
            for (int q = 0; q < 8; q++) {
                if (j + q < nn) { a0 += bflo(v[q]); a1 += bfhi(v[q]); }
            }
        }
    }
    unsigned short u[2] = {f2bf(a0), f2bf(a1)};
    *(unsigned int*)(pooled_b + n * DIM + c2) = *(unsigned int*)u;
}

// fused Linear1 -> ReLU -> Linear2 -> BN -> ReLU for a 64-row tile.
// A-fragments loaded straight from bf16 row-major pooled_b (no LDS staging).
__global__ __launch_bounds__(256) void mlp_kernel(
    const unsigned short* __restrict__ pooled_b,
    const unsigned short* __restrict__ wp1,
    const unsigned short* __restrict__ wp2,
    const float* __restrict__ b1,
    const float* __restrict__ b2,
    const float* __restrict__ bnscale,
    const float* __restrict__ bnshift,
    float* __restrict__ h_out,
    unsigned short* __restrict__ hb_out) {
    __shared__ __align__(16) unsigned short zfrag[4][4][64][8];  // z1 shuffle, wave-private
    const int tid = threadIdx.x;
    const int wave = tid >> 6, lane = tid & 63;
    const int m0 = blockIdx.x * 64;
    const int colc = lane & 15;
    const int quad = lane >> 4;
    const int arow = m0 + wave * 16 + colc;
    const int arow_c = arow < N_NODES ? arow : N_NODES - 1;

    bf16x8 a[4];
#pragma unroll
    for (int ks = 0; ks < 4; ks++)
        a[ks] = *(const bf16x8*)(pooled_b + arow_c * DIM + ks * 32 + quad * 8);

    f32x4 acc[8];
#pragma unroll
    for (int nt = 0; nt < 8; nt++) {
        acc[nt] = (f32x4){0.f, 0.f, 0.f, 0.f};
#pragma unroll
        for (int ks = 0; ks < 4; ks++) {
            bf16x8 b = *(const bf16x8*)(wp1 + ((ks * 8 + nt) * 64 + lane) * 8);
            acc[nt] = __builtin_amdgcn_mfma_f32_16x16x32_bf16(a[ks], b, acc[nt], 0, 0, 0);
        }
    }

    // bias + ReLU, write z1 to LDS in A-fragment layout (wave-private region)
#pragma unroll
    for (int nt = 0; nt < 8; nt++) {
        int n = nt * 16 + colc;
        float bias = b1[n];
#pragma unroll
        for (int r = 0; r < 4; r++) {
            float v = acc[nt][r] + bias;
            v = v > 0.f ? v : 0.f;
            int row16 = quad * 4 + r;
            zfrag[wave][n >> 5][(((n >> 3) & 3) << 4) | row16][n & 7] = f2bf(v);
        }
    }

#pragma unroll
    for (int ks = 0; ks < 4; ks++) a[ks] = *(const bf16x8*)(&zfrag[wave][ks][lane][0]);

    f32x4 acc2[8];
#pragma unroll
    for (int nt = 0; nt < 8; nt++) {
        acc2[nt] = (f32x4){0.f, 0.f, 0.f, 0.f};
#pragma unroll
        for (int ks = 0; ks < 4; ks++) {
            bf16x8 b = *(const bf16x8*)(wp2 + ((ks * 8 + nt) * 64 + lane) * 8);
            acc2[nt] = __builtin_amdgcn_mfma_f32_16x16x32_bf16(a[ks], b, acc2[nt], 0, 0, 0);
        }
    }

    // epilogue: +b2, BN, ReLU; nontemporal fp32 out (write-only) + bf16 shadow
#pragma unroll
    for (int nt = 0; nt < 8; nt++) {
        int n = nt * 16 + colc;
        float bias = b2[n];
        float sc = bnscale[n], sh = bnshift[n];
#pragma unroll
        for (int r = 0; r < 4; r++) {
            int row = m0 + wave * 16 + quad * 4 + r;
            if (row < N_NODES) {
                float z = acc2[nt][r] + bias;
                z = z * sc + sh;
                z = z > 0.f ? z : 0.f;
                __builtin_nontemporal_store(z, &h_out[row * DIM + n]);
                hb_out[row * DIM + n] = f2bf(z);
            }
        }
    }
}

// ---- launch --------------------------------------------------------------

extern "C" void kernel_launch(void* const* d_in, const int* in_sizes, int n_in,
                              void* d_out, int out_size, void* d_ws, size_t ws_size,
                              hipStream_t stream) {
    const float* x     = (const float*)d_in[0];
    const int* esrc    = (const int*)d_in[1];
    const int* edst    = (const int*)d_in[2];
    const float* eps   = (const float*)d_in[3];
    const float* W1    = (const float*)d_in[4];
    const float* b1    = (const float*)d_in[5];
    const float* W2    = (const float*)d_in[6];
    const float* b2    = (const float*)d_in[7];
    const float* gam   = (const float*)d_in[8];
    const float* bet   = (const float*)d_in[9];
    const float* bmean = (const float*)d_in[10];
    const float* bvar  = (const float*)d_in[11];
    float* out = (float*)d_out;

    char* ws = (char*)d_ws;
    unsigned short* hb0   = (unsigned short*)(ws);               // 12,800,000 B
    unsigned short* hb1   = (unsigned short*)(ws + 12800000);    // 12,800,000 B
    int*   col        = (int*)  (ws + 25600000);                 //  3,200,000 B
    int*   row_start  = (int*)  (ws + 28800000);                 //    200,004 B
    int*   cursor     = (int*)  (ws + 29000008);                 //    200,000 B
    int*   cnt        = (int*)  (ws + 29200008);                 //    200,000 B
    unsigned short* wpack = (unsigned short*)(ws + 29400008);    //    327,680 B
    float* bnscale    = (float*)(ws + 29727688);                 //      2,560 B
    float* bnshift    = (float*)(ws + 29730248);                 //      2,560 B
    unsigned short* pooled_b = (unsigned short*)(ws + 29735048); // 12,800,000 B

    init_zero_kernel<<<((N_NODES * DIM) / 4 + N_NODES + 255) / 256, 256, 0, stream>>>(
        x, out, hb0, cnt);
    hist_kernel<<<(N_EDGES + 255) / 256, 256, 0, stream>>>(edst, cnt);
    scan_kernel<<<1, 1024, 0, stream>>>(cnt, row_start, cursor);
    fill_kernel<<<(N_EDGES + 255) / 256, 256, 0, stream>>>(esrc, edst, cursor, col);
    prep_kernel<<<(N_LAYERS * 2 * 2048 + N_LAYERS * DIM + 255) / 256, 256, 0, stream>>>(
        W1, W2, wpack, gam, bet, bmean, bvar, bnscale, bnshift);

    const int pool_blocks = (N_NODES + 3) / 4;   // 12500
    const int mlp_blocks  = (N_NODES + 63) / 64; // 782
    unsigned short* hbuf[2] = {hb0, hb1};
    for (int l = 0; l < N_LAYERS; l++) {
        float* h_next = out + (size_t)(l + 1) * N_NODES * DIM;
        pool_kernel<<<pool_blocks, 256, 0, stream>>>(hbuf[l & 1], row_start, col, eps + l,
                                                     pooled_b);
        mlp_kernel<<<mlp_blocks, 256, 0, stream>>>(
            pooled_b,
            wpack + (size_t)(l * 2) * 16384,
            wpack + (size_t)(l * 2 + 1) * 16384,
            b1 + l * DIM, b2 + l * DIM,
            bnscale + l * DIM, bnshift + l * DIM,
            h_next, hbuf[(l + 1) & 1]);
    }
}